// Round 4
// baseline (149.197 us; speedup 1.0000x reference)
//
#include <hip/hip_runtime.h>
#include <hip/hip_fp16.h>

#define KNB 31
#define CH 64
#define TEMP_INV 10.0f   // 1 / temperature(0.1)

typedef _Float16 h2 __attribute__((ext_vector_type(2)));

// ---------------------------------------------------------------------------
// ws layout:
//   bytes [0, 16)        : double ws[2]  (sum(loss*mask), sum(mask))
//   bytes [256, 256+2NC) : __half feature table (fp16 path only)
// ---------------------------------------------------------------------------

__global__ void ch_init_ws(double* __restrict__ ws) {
    ws[0] = 0.0;
    ws[1] = 0.0;
}

// features f32 -> fp16 table (8 floats/thread); thread 0 also zeroes ws.
__global__ __launch_bounds__(256) void ch_cvt(
    const float* __restrict__ in, __half* __restrict__ out,
    double* __restrict__ ws, int total8)
{
    const int idx = blockIdx.x * blockDim.x + threadIdx.x;
    if (idx == 0) {
        ws[0] = 0.0;
        ws[1] = 0.0;
    }
    if (idx >= total8) return;
    const float4* ip = reinterpret_cast<const float4*>(in) + (size_t)idx * 2;
    const float4 a = ip[0];
    const float4 b = ip[1];
    union { uint4 u; __half2 h[4]; } o;
    o.h[0] = __floats2half2_rn(a.x, a.y);
    o.h[1] = __floats2half2_rn(a.z, a.w);
    o.h[2] = __floats2half2_rn(b.x, b.y);
    o.h[3] = __floats2half2_rn(b.z, b.w);
    reinterpret_cast<uint4*>(out)[idx] = o.u;
}

__device__ __forceinline__ float dot2acc(h2 d, float s) {
#if defined(__has_builtin) && __has_builtin(__builtin_amdgcn_fdot2)
    return __builtin_amdgcn_fdot2(d, d, s, false);
#else
    const float x = (float)d[0], y = (float)d[1];
    return s + x * x + y * y;
#endif
}

// Transposed: 8 lanes per point; lane sub owns neighbors j = 8g + sub (g<4)
// and computes each FULL 64-ch distance itself (no per-neighbor shuffles).
__global__ __launch_bounds__(256, 4) void ch_mainT(
    const __half* __restrict__ tab,     // (N, 64) fp16
    const int*    __restrict__ labels,  // (N,)
    const int*    __restrict__ nidx,    // (N, 31)
    double*       __restrict__ ws,
    int n)
{
    const int t   = threadIdx.x;
    const int i   = blockIdx.x * (256 / 8) + (t >> 3);
    const int sub = t & 7;

    float loss_w = 0.0f;
    float pm_f   = 0.0f;

    if (i < n) {
        // ---- own row: 128 B fp16 -> 8 x uint4 (32 VGPR), broadcast load ----
        const uint4* ap = reinterpret_cast<const uint4*>(tab + (size_t)i * CH);
        uint4 A[8];
        #pragma unroll
        for (int q = 0; q < 8; ++q) A[q] = ap[q];

        const int lab = labels[i];

        unsigned mymask = 0u;   // posmask bits at true j positions
        float dloc[4];

        #pragma unroll
        for (int g = 0; g < 4; ++g) {
            const int j     = g * 8 + sub;
            const bool valid = (j < KNB);            // only lane 7, g=3 invalid
            const int jc    = valid ? j : (KNB - 1); // clamped, in-bounds
            const int nj    = nidx[(size_t)i * KNB + jc];

            const uint4* bp = reinterpret_cast<const uint4*>(tab + (size_t)nj * CH);
            float s = 0.0f;
            #pragma unroll
            for (int q = 0; q < 8; ++q) {
                union { uint4 u; h2 h[4]; } Bv, Av;
                Bv.u = bp[q];
                Av.u = A[q];
                #pragma unroll
                for (int k = 0; k < 4; ++k) {
                    const h2 d = Av.h[k] - Bv.h[k];
                    s = dot2acc(d, s);
                }
            }

            const bool pm = valid && (labels[nj] == lab);
            mymask |= pm ? (1u << jc) : 0u;
            dloc[g] = valid ? (sqrtf(s) + 1e-8f) : 1e30f;
        }

        // ---- combine across the 8-lane group (12 shuffles total) ----------
        mymask |= __shfl_xor((int)mymask, 1);
        mymask |= __shfl_xor((int)mymask, 2);
        mymask |= __shfl_xor((int)mymask, 4);

        float mn = fminf(fminf(dloc[0], dloc[1]), fminf(dloc[2], dloc[3]));
        mn = fminf(mn, __shfl_xor(mn, 1));
        mn = fminf(mn, __shfl_xor(mn, 2));
        mn = fminf(mn, __shfl_xor(mn, 4));

        float se = 0.0f, sp = 0.0f;
        #pragma unroll
        for (int g = 0; g < 4; ++g) {
            const int j = g * 8 + sub;
            const float e = (j < KNB) ? __expf((mn - dloc[g]) * TEMP_INV) : 0.0f;
            se += e;
            sp += ((mymask >> (j & 31)) & 1u) ? e : 0.0f;  // bit 31 never set
        }
        se += __shfl_xor(se, 1);
        se += __shfl_xor(se, 2);
        se += __shfl_xor(se, 4);
        sp += __shfl_xor(sp, 1);
        sp += __shfl_xor(sp, 2);
        sp += __shfl_xor(sp, 4);

        const int cnt = __popc(mymask);
        if (sub == 0 && cnt > 0 && cnt < KNB) {
            loss_w = -logf(sp / se + 1e-8f);
            pm_f   = 1.0f;
        }
    }

    // ---- block reduction, one double atomic per block -----------------------
    __shared__ float s_l[256];
    __shared__ float s_c[256];
    s_l[t] = loss_w;
    s_c[t] = pm_f;
    __syncthreads();
    #pragma unroll
    for (int off = 128; off > 0; off >>= 1) {
        if (t < off) {
            s_l[t] += s_l[t + off];
            s_c[t] += s_c[t + off];
        }
        __syncthreads();
    }
    if (t == 0) {
        atomicAdd(ws,     (double)s_l[0]);
        atomicAdd(ws + 1, (double)s_c[0]);
    }
}

// f32 fallback (only if ws can't hold the fp16 table): 4 lanes/point, online.
__global__ __launch_bounds__(256) void ch_main4f(
    const float* __restrict__ feat,
    const int*   __restrict__ labels,
    const int*   __restrict__ nidx,
    double*      __restrict__ ws,
    int n)
{
    const int t   = threadIdx.x;
    const int i   = blockIdx.x * (256 / 4) + (t >> 2);
    const int sub = t & 3;

    float loss_w = 0.0f;
    float pm_f   = 0.0f;

    if (i < n) {
        float f[16];
        const float4* ap = reinterpret_cast<const float4*>(feat + (size_t)i * CH + sub * 16);
        #pragma unroll
        for (int q = 0; q < 4; ++q) {
            const float4 v = ap[q];
            f[4 * q] = v.x; f[4 * q + 1] = v.y; f[4 * q + 2] = v.z; f[4 * q + 3] = v.w;
        }
        const int lab = labels[i];
        float m = -1e30f, se = 0.0f, sp = 0.0f;
        int cnt = 0;
        for (int j = 0; j < KNB; ++j) {
            const int nj = nidx[(size_t)i * KNB + j];
            const float4* bp = reinterpret_cast<const float4*>(feat + (size_t)nj * CH + sub * 16);
            float s = 0.0f;
            #pragma unroll
            for (int q = 0; q < 4; ++q) {
                const float4 v = bp[q];
                float d;
                d = f[4 * q]     - v.x; s += d * d;
                d = f[4 * q + 1] - v.y; s += d * d;
                d = f[4 * q + 2] - v.z; s += d * d;
                d = f[4 * q + 3] - v.w; s += d * d;
            }
            s += __shfl_xor(s, 1);
            s += __shfl_xor(s, 2);
            const float l = -(sqrtf(s) + 1e-8f);
            const bool pm = (labels[nj] == lab);
            cnt += pm ? 1 : 0;
            if (l > m) {
                const float r = __expf((m - l) * TEMP_INV);
                se *= r; sp *= r; m = l;
            }
            const float e = __expf((l - m) * TEMP_INV);
            se += e;
            if (pm) sp += e;
        }
        if (sub == 0 && cnt > 0 && cnt < KNB) {
            loss_w = -logf(sp / se + 1e-8f);
            pm_f   = 1.0f;
        }
    }

    __shared__ float s_l[256];
    __shared__ float s_c[256];
    s_l[t] = loss_w;
    s_c[t] = pm_f;
    __syncthreads();
    #pragma unroll
    for (int off = 128; off > 0; off >>= 1) {
        if (t < off) {
            s_l[t] += s_l[t + off];
            s_c[t] += s_c[t + off];
        }
        __syncthreads();
    }
    if (t == 0) {
        atomicAdd(ws,     (double)s_l[0]);
        atomicAdd(ws + 1, (double)s_c[0]);
    }
}

__global__ void ch_finalize(const double* __restrict__ ws, float* __restrict__ out) {
    double c = ws[1];
    if (c < 1.0) c = 1.0;
    out[0] = (float)(ws[0] / c);   // WEIGHT = 1.0
}

extern "C" void kernel_launch(void* const* d_in, const int* in_sizes, int n_in,
                              void* d_out, int out_size, void* d_ws, size_t ws_size,
                              hipStream_t stream) {
    const float* feat   = (const float*)d_in[0];
    const int*   labels = (const int*)d_in[1];
    const int*   nidx   = (const int*)d_in[2];
    float*       out    = (float*)d_out;
    double*      ws     = (double*)d_ws;

    const int n = in_sizes[1];                 // N = 100000
    const size_t tab_bytes = (size_t)n * CH * sizeof(__half);
    const bool fp16_ok = ws_size >= 256 + tab_bytes;

    if (fp16_ok) {
        __half* tab = reinterpret_cast<__half*>((char*)d_ws + 256);
        const int total8 = n * CH / 8;
        ch_cvt<<<(total8 + 255) / 256, 256, 0, stream>>>(feat, tab, ws, total8);
        const int blocks = (n + 31) / 32;      // 32 points per 256-thread block
        ch_mainT<<<blocks, 256, 0, stream>>>(tab, labels, nidx, ws, n);
    } else {
        ch_init_ws<<<1, 1, 0, stream>>>(ws);
        const int blocks = (n + 63) / 64;
        ch_main4f<<<blocks, 256, 0, stream>>>(feat, labels, nidx, ws, n);
    }

    ch_finalize<<<1, 1, 0, stream>>>(ws, out);
}

// Round 5
// 115.991 us; speedup vs baseline: 1.2863x; 1.2863x over previous
//
#include <hip/hip_runtime.h>
#include <hip/hip_fp16.h>

#define KNB 31
#define CH 64
#define TEMP_INV 10.0f   // 1 / temperature(0.1)

typedef _Float16 h2 __attribute__((ext_vector_type(2)));

// ---------------------------------------------------------------------------
// ws layout:
//   bytes [0, 16)        : double ws[2]  (sum(loss*mask), sum(mask))
//   bytes [256, 256+2NC) : __half feature table (fp16 path only)
// ---------------------------------------------------------------------------

__global__ void ch_init_ws(double* __restrict__ ws) {
    ws[0] = 0.0;
    ws[1] = 0.0;
}

// features f32 -> fp16 table (8 floats/thread); thread 0 also zeroes ws.
__global__ __launch_bounds__(256) void ch_cvt(
    const float* __restrict__ in, __half* __restrict__ out,
    double* __restrict__ ws, int total8)
{
    const int idx = blockIdx.x * blockDim.x + threadIdx.x;
    if (idx == 0) {
        ws[0] = 0.0;
        ws[1] = 0.0;
    }
    if (idx >= total8) return;
    const float4* ip = reinterpret_cast<const float4*>(in) + (size_t)idx * 2;
    const float4 a = ip[0];
    const float4 b = ip[1];
    union { uint4 u; __half2 h[4]; } o;
    o.h[0] = __floats2half2_rn(a.x, a.y);
    o.h[1] = __floats2half2_rn(a.z, a.w);
    o.h[2] = __floats2half2_rn(b.x, b.y);
    o.h[3] = __floats2half2_rn(b.z, b.w);
    reinterpret_cast<uint4*>(out)[idx] = o.u;
}

__device__ __forceinline__ float dot2acc(h2 d, float s) {
#if defined(__has_builtin) && __has_builtin(__builtin_amdgcn_fdot2)
    return __builtin_amdgcn_fdot2(d, d, s, false);
#else
    const float x = (float)d[0], y = (float)d[1];
    return s + x * x + y * y;
#endif
}

// 4 lanes/point, quad-cooperative gathers (R2 pattern), but phase-split:
// phase A = 31 INDEPENDENT gather+dist iterations -> dist in LDS (no spill);
// phase B = per-lane softmax over j == sub (mod 4) (31 exps/point, not 124).
__global__ __launch_bounds__(256) void ch_main_p(
    const __half* __restrict__ tab,     // (N, 64) fp16
    const int*    __restrict__ labels,  // (N,)
    const int*    __restrict__ nidx,    // (N, 31)
    double*       __restrict__ ws,
    int n)
{
    const int t   = threadIdx.x;
    const int pt  = t >> 2;               // point slot in block, 0..63
    const int sub = t & 3;
    const int i   = blockIdx.x * 64 + pt;

    __shared__ float dl[64][33];          // stride 33 -> conflict-free

    float loss_w = 0.0f;
    float pm_f   = 0.0f;

    unsigned pmask = 0u;

    if (i < n) {
        // own 16 channels (32 B fp16) -> 2 x uint4
        union { uint4 u[2]; h2 h[8]; } A;
        const uint4* ap = reinterpret_cast<const uint4*>(tab + (size_t)i * CH + sub * 16);
        A.u[0] = ap[0];
        A.u[1] = ap[1];

        const int lab = labels[i];

        // ---- phase A: 31 independent gather->dist iterations ------------
        #pragma unroll 4
        for (int j = 0; j < KNB; ++j) {
            const int nj = nidx[(size_t)i * KNB + j];      // quad-broadcast

            union { uint4 u[2]; h2 h[8]; } B;
            const uint4* bp = reinterpret_cast<const uint4*>(tab + (size_t)nj * CH + sub * 16);
            B.u[0] = bp[0];
            B.u[1] = bp[1];

            float s = 0.0f;
            #pragma unroll
            for (int q = 0; q < 8; ++q) {
                const h2 d = A.h[q] - B.h[q];
                s = dot2acc(d, s);
            }
            s += __shfl_xor(s, 1);
            s += __shfl_xor(s, 2);

            pmask |= (labels[nj] == lab) ? (1u << j) : 0u; // quad-broadcast load

            if ((j & 3) == sub)                            // one writer per j
                dl[pt][j] = sqrtf(s) + 1e-8f;
        }
    }

    __syncthreads();   // uniform; separates LDS write/read across the block

    if (i < n) {
        // ---- phase B: lane handles j = sub, sub+4, ..., (7 or 8 of them) --
        float mn_l = 1e30f;
        float dj[8];
        #pragma unroll
        for (int q = 0; q < 8; ++q) {
            const int j = sub + 4 * q;
            dj[q] = (j < KNB) ? dl[pt][j] : 1e30f;
            mn_l = fminf(mn_l, dj[q]);
        }
        mn_l = fminf(mn_l, __shfl_xor(mn_l, 1));
        mn_l = fminf(mn_l, __shfl_xor(mn_l, 2));           // global min dist

        float se = 0.0f, sp = 0.0f;
        #pragma unroll
        for (int q = 0; q < 8; ++q) {
            const int j = sub + 4 * q;
            const float e = (j < KNB) ? __expf((mn_l - dj[q]) * TEMP_INV) : 0.0f;
            se += e;
            sp += ((pmask >> (j & 31)) & 1u) ? e : 0.0f;   // bit 31 never set
        }
        se += __shfl_xor(se, 1);
        se += __shfl_xor(se, 2);
        sp += __shfl_xor(sp, 1);
        sp += __shfl_xor(sp, 2);

        const int cnt = __popc(pmask);
        if (sub == 0 && cnt > 0 && cnt < KNB) {
            loss_w = -logf(sp / se + 1e-8f);
            pm_f   = 1.0f;
        }
    }

    // ---- block reduction, one double atomic per block -----------------------
    __shared__ float s_l[256];
    __shared__ float s_c[256];
    s_l[t] = loss_w;
    s_c[t] = pm_f;
    __syncthreads();
    #pragma unroll
    for (int off = 128; off > 0; off >>= 1) {
        if (t < off) {
            s_l[t] += s_l[t + off];
            s_c[t] += s_c[t + off];
        }
        __syncthreads();
    }
    if (t == 0) {
        atomicAdd(ws,     (double)s_l[0]);
        atomicAdd(ws + 1, (double)s_c[0]);
    }
}

// f32 fallback (only if ws can't hold the fp16 table): R2 online structure.
__global__ __launch_bounds__(256) void ch_main4f(
    const float* __restrict__ feat,
    const int*   __restrict__ labels,
    const int*   __restrict__ nidx,
    double*      __restrict__ ws,
    int n)
{
    const int t   = threadIdx.x;
    const int i   = blockIdx.x * (256 / 4) + (t >> 2);
    const int sub = t & 3;

    float loss_w = 0.0f;
    float pm_f   = 0.0f;

    if (i < n) {
        float f[16];
        const float4* ap = reinterpret_cast<const float4*>(feat + (size_t)i * CH + sub * 16);
        #pragma unroll
        for (int q = 0; q < 4; ++q) {
            const float4 v = ap[q];
            f[4 * q] = v.x; f[4 * q + 1] = v.y; f[4 * q + 2] = v.z; f[4 * q + 3] = v.w;
        }
        const int lab = labels[i];
        float m = -1e30f, se = 0.0f, sp = 0.0f;
        int cnt = 0;
        for (int j = 0; j < KNB; ++j) {
            const int nj = nidx[(size_t)i * KNB + j];
            const float4* bp = reinterpret_cast<const float4*>(feat + (size_t)nj * CH + sub * 16);
            float s = 0.0f;
            #pragma unroll
            for (int q = 0; q < 4; ++q) {
                const float4 v = bp[q];
                float d;
                d = f[4 * q]     - v.x; s += d * d;
                d = f[4 * q + 1] - v.y; s += d * d;
                d = f[4 * q + 2] - v.z; s += d * d;
                d = f[4 * q + 3] - v.w; s += d * d;
            }
            s += __shfl_xor(s, 1);
            s += __shfl_xor(s, 2);
            const float l = -(sqrtf(s) + 1e-8f);
            const bool pm = (labels[nj] == lab);
            cnt += pm ? 1 : 0;
            if (l > m) {
                const float r = __expf((m - l) * TEMP_INV);
                se *= r; sp *= r; m = l;
            }
            const float e = __expf((l - m) * TEMP_INV);
            se += e;
            if (pm) sp += e;
        }
        if (sub == 0 && cnt > 0 && cnt < KNB) {
            loss_w = -logf(sp / se + 1e-8f);
            pm_f   = 1.0f;
        }
    }

    __shared__ float s_l[256];
    __shared__ float s_c[256];
    s_l[t] = loss_w;
    s_c[t] = pm_f;
    __syncthreads();
    #pragma unroll
    for (int off = 128; off > 0; off >>= 1) {
        if (t < off) {
            s_l[t] += s_l[t + off];
            s_c[t] += s_c[t + off];
        }
        __syncthreads();
    }
    if (t == 0) {
        atomicAdd(ws,     (double)s_l[0]);
        atomicAdd(ws + 1, (double)s_c[0]);
    }
}

__global__ void ch_finalize(const double* __restrict__ ws, float* __restrict__ out) {
    double c = ws[1];
    if (c < 1.0) c = 1.0;
    out[0] = (float)(ws[0] / c);   // WEIGHT = 1.0
}

extern "C" void kernel_launch(void* const* d_in, const int* in_sizes, int n_in,
                              void* d_out, int out_size, void* d_ws, size_t ws_size,
                              hipStream_t stream) {
    const float* feat   = (const float*)d_in[0];
    const int*   labels = (const int*)d_in[1];
    const int*   nidx   = (const int*)d_in[2];
    float*       out    = (float*)d_out;
    double*      ws     = (double*)d_ws;

    const int n = in_sizes[1];                 // N = 100000
    const size_t tab_bytes = (size_t)n * CH * sizeof(__half);
    const bool fp16_ok = ws_size >= 256 + tab_bytes;

    if (fp16_ok) {
        __half* tab = reinterpret_cast<__half*>((char*)d_ws + 256);
        const int total8 = n * CH / 8;
        ch_cvt<<<(total8 + 255) / 256, 256, 0, stream>>>(feat, tab, ws, total8);
        const int blocks = (n + 63) / 64;      // 64 points per 256-thread block
        ch_main_p<<<blocks, 256, 0, stream>>>(tab, labels, nidx, ws, n);
    } else {
        ch_init_ws<<<1, 1, 0, stream>>>(ws);
        const int blocks = (n + 63) / 64;
        ch_main4f<<<blocks, 256, 0, stream>>>(feat, labels, nidx, ws, n);
    }

    ch_finalize<<<1, 1, 0, stream>>>(ws, out);
}